// Round 4
// baseline (298.263 us; speedup 1.0000x reference)
//
#include <hip/hip_runtime.h>
#include <hip/hip_bf16.h>
#include <stdint.h>

#define LN_EPS 1e-5f

typedef __attribute__((ext_vector_type(4))) float f32x4;
typedef __attribute__((ext_vector_type(8))) short bf16x8;

#define D_ 1024
#define P_ 512
#define N_ 32768   // B*S rows

// ---------------- kernel: scatter W rows into W2f ----------------
// W2f[c,p] = sum_{d: s5[d]==c} W[d,p];  b2[c] = sum_{d: s5[d]==c} b[d]
__global__ void k_scatter(const float* __restrict__ W, const float* __restrict__ bias,
                          const int* __restrict__ s5,
                          float* __restrict__ w2f, float* __restrict__ b2) {
  int d = blockIdx.x;                  // 0..1023
  int c = s5[d];
  const float* wrow = W + (size_t)d * P_;
  float* dst = w2f + (size_t)c * P_;
  for (int p = threadIdx.x; p < P_; p += 256)
    atomicAdd(&dst[p], wrow[p]);
  if (threadIdx.x == 0) atomicAdd(&b2[c], bias[d]);
}

// ---------------- kernel: W2f -> bf16 ----------------
__global__ void k_conv(const float* __restrict__ w2f, __hip_bfloat16* __restrict__ w2b) {
  int i = blockIdx.x * 256 + threadIdx.x;
  if (i < D_ * P_) w2b[i] = __float2bfloat16(w2f[i]);
}

// ---------------- kernel: LayerNorm + gather -> g (bf16 [N_,P_]) ----------------
__global__ __launch_bounds__(256) void k_ln_gather(
    const float* __restrict__ x, const float* __restrict__ lnw,
    const float* __restrict__ lnb, const int* __restrict__ s3,
    __hip_bfloat16* __restrict__ g) {
  __shared__ float row[D_];
  __shared__ float psum[4], psum2[4];
  const int n = blockIdx.x;
  const int t = threadIdx.x;
  const float* xr = x + (size_t)n * D_;
  float4 v = ((const float4*)xr)[t];       // 256 threads * 4 floats = 1024
  ((float4*)row)[t] = v;
  float s  = v.x + v.y + v.z + v.w;
  float s2 = v.x*v.x + v.y*v.y + v.z*v.z + v.w*v.w;
  #pragma unroll
  for (int off = 32; off > 0; off >>= 1) {
    s  += __shfl_down(s, off);
    s2 += __shfl_down(s2, off);
  }
  const int lane = t & 63, wid = t >> 6;
  if (lane == 0) { psum[wid] = s; psum2[wid] = s2; }
  __syncthreads();
  const float tot  = psum[0] + psum[1] + psum[2] + psum[3];
  const float tot2 = psum2[0] + psum2[1] + psum2[2] + psum2[3];
  const float mu  = tot * (1.f / D_);
  const float var = tot2 * (1.f / D_) - mu * mu;
  const float inv = rsqrtf(var + LN_EPS);
  __hip_bfloat16* gr = g + (size_t)n * P_;
  // two gathered outputs per thread, one 4B store
  const int i0 = s3[2*t], i1 = s3[2*t+1];
  const float v0 = (row[i0] - mu) * inv * lnw[i0] + lnb[i0];
  const float v1 = (row[i1] - mu) * inv * lnw[i1] + lnb[i1];
  union { __hip_bfloat16 h; unsigned short u; } c0, c1;
  c0.h = __float2bfloat16(v0);
  c1.h = __float2bfloat16(v1);
  unsigned int packed = (unsigned int)c0.u | ((unsigned int)c1.u << 16);
  ((unsigned int*)gr)[t] = packed;
}

// ---------------- kernel: bf16 MFMA GEMM + residual + bias ----------------
// out[n,c] = hid[n,c] + sum_p g[n,p]*W2[c,p] + b2[c]
// NO LDS, NO BARRIERS: A- and B-fragments load directly from global.
// Each frag load = 16 rows x 64B contiguous = 16 fully-consumed cache lines.
// W2b (1 MB) is L2-resident; g-strip shared by the 8 bn-siblings, colocated
// on one XCD by the block swizzle (round-2-proven FETCH reduction).
// 128x128 tile, 4 waves (2x2), wave-tile 64x64, 16x16x32 bf16 MFMA, acc 4x4.
__global__ __launch_bounds__(256) void k_gemm(
    const __hip_bfloat16* __restrict__ g,    // [N_,P_]
    const __hip_bfloat16* __restrict__ w2b,  // [D_,P_]
    const float* __restrict__ b2,            // [D_]
    const float* __restrict__ hid,           // [N_,D_]
    float* __restrict__ out) {               // [N_,D_]
  // XCD-aware swizzle: XCD x gets 32 contiguous bm-strips; the 8 bn-siblings
  // of each strip are consecutive on the same XCD (share the g strip in L2).
  const int bid = blockIdx.x;                // 0..2047
  const int x = bid & 7;                     // this block's XCD
  const int kq = bid >> 3;                   // 0..255
  const int bm = (x * 32 + (kq >> 3)) * 128; // row tile
  const int bn = (kq & 7) * 128;             // col tile

  const int t = threadIdx.x;
  const int lane = t & 63;
  const int wid = t >> 6;
  const int wr = wid >> 1, wc = wid & 1;     // 2x2 waves, 64x64 subtile each

  // per-lane fragment base pointers (elem offset (lane>>4)*8 within k-group)
  const __hip_bfloat16* pA = g   + (size_t)(bm + wr * 64 + (lane & 15)) * P_ + ((lane >> 4) << 3);
  const __hip_bfloat16* pB = w2b + (size_t)(bn + wc * 64 + (lane & 15)) * P_ + ((lane >> 4) << 3);

  f32x4 acc[4][4] = {};

  #pragma unroll
  for (int ks = 0; ks < 8; ++ks) {           // K = 512, 64 per iter
    bf16x8 af[2][4], bfr[2][4];
    #pragma unroll
    for (int kk = 0; kk < 2; ++kk) {
      const int ko = ks * 64 + kk * 32;      // elem offset
      #pragma unroll
      for (int mi = 0; mi < 4; ++mi)
        af[kk][mi] = *(const bf16x8*)(pA + (size_t)mi * 16 * P_ + ko);
      #pragma unroll
      for (int ni = 0; ni < 4; ++ni)
        bfr[kk][ni] = *(const bf16x8*)(pB + (size_t)ni * 16 * P_ + ko);
    }
    #pragma unroll
    for (int kk = 0; kk < 2; ++kk)
      #pragma unroll
      for (int mi = 0; mi < 4; ++mi)
        #pragma unroll
        for (int ni = 0; ni < 4; ++ni)
          acc[mi][ni] = __builtin_amdgcn_mfma_f32_16x16x32_bf16(
              af[kk][mi], bfr[kk][ni], acc[mi][ni], 0, 0, 0);
  }

  // epilogue: C/D layout col=lane&15 (N), row=(lane>>4)*4+reg (M).
  // nontemporal: hid has no 3rd read, out is never re-read -> don't pollute
  // the XCD-L2 holding g/w2b.
  const int row0 = bm + wr * 64 + ((lane >> 4) << 2);
  const int col0 = bn + wc * 64 + (lane & 15);
  #pragma unroll
  for (int ni = 0; ni < 4; ++ni) {
    const int col = col0 + ni * 16;
    const float bias = b2[col];
    #pragma unroll
    for (int mi = 0; mi < 4; ++mi) {
      const int rw = row0 + mi * 16;
      #pragma unroll
      for (int r4 = 0; r4 < 4; ++r4) {
        const size_t idx = (size_t)(rw + r4) * D_ + col;
        const float h = __builtin_nontemporal_load(hid + idx);
        __builtin_nontemporal_store(h + acc[mi][ni][r4] + bias, out + idx);
      }
    }
  }
}

extern "C" void kernel_launch(void* const* d_in, const int* in_sizes, int n_in,
                              void* d_out, int out_size, void* d_ws, size_t ws_size,
                              hipStream_t stream) {
  const float* hid  = (const float*)d_in[0];
  const float* lnw  = (const float*)d_in[1];
  const float* lnb  = (const float*)d_in[2];
  const float* W    = (const float*)d_in[3];
  const float* bias = (const float*)d_in[4];
  const int*   s3   = (const int*)d_in[5];
  const int*   s5   = (const int*)d_in[6];
  float* out = (float*)d_out;

  // workspace layout:
  //   [0, 2MB)            W2f  fp32 [1024][512]
  //   [2MB, +4KB)         b2   fp32 [1024]
  //   [2MB+4KB, +1MB)     W2b  bf16 [1024][512]
  //   [3MB+4KB, +32MB)    g    bf16 [32768][512]
  char* ws = (char*)d_ws;
  float*          w2f = (float*)ws;
  float*          b2  = (float*)(ws + 2097152);
  __hip_bfloat16* w2b = (__hip_bfloat16*)(ws + 2101248);
  __hip_bfloat16* g   = (__hip_bfloat16*)(ws + 3149824);

  hipMemsetAsync(ws, 0, 2101248, stream);   // zero W2f + b2
  k_scatter<<<dim3(1024), dim3(256), 0, stream>>>(W, bias, s5, w2f, b2);
  k_conv   <<<dim3(2048), dim3(256), 0, stream>>>(w2f, w2b);
  k_ln_gather<<<dim3(N_), dim3(256), 0, stream>>>(hid, lnw, lnb, s3, g);
  k_gemm   <<<dim3(2048), dim3(256), 0, stream>>>(g, w2b, b2, hid, out);
}

// Round 5
// 150.777 us; speedup vs baseline: 1.9782x; 1.9782x over previous
//
#include <hip/hip_runtime.h>
#include <hip/hip_bf16.h>
#include <stdint.h>

#define LN_EPS 1e-5f

typedef __attribute__((ext_vector_type(4))) float f32x4;
typedef __attribute__((ext_vector_type(8))) short bf16x8;

#define D_ 1024
#define P_ 512
#define N_ 32768   // B*S rows

// async global->LDS, 16B per lane
__device__ __forceinline__ void gload_lds16(const void* gsrc, void* ldst) {
  __builtin_amdgcn_global_load_lds(
      (const __attribute__((address_space(1))) void*)gsrc,
      (__attribute__((address_space(3))) void*)ldst,
      16, 0, 0);
}

// ---------------- kernel: scatter W rows into W2f ----------------
// W2f[c,p] = sum_{d: s5[d]==c} W[d,p];  b2[c] = sum_{d: s5[d]==c} b[d]
__global__ void k_scatter(const float* __restrict__ W, const float* __restrict__ bias,
                          const int* __restrict__ s5,
                          float* __restrict__ w2f, float* __restrict__ b2) {
  int d = blockIdx.x;                  // 0..1023
  int c = s5[d];
  const float* wrow = W + (size_t)d * P_;
  float* dst = w2f + (size_t)c * P_;
  for (int p = threadIdx.x; p < P_; p += 256)
    atomicAdd(&dst[p], wrow[p]);
  if (threadIdx.x == 0) atomicAdd(&b2[c], bias[d]);
}

// ---------------- kernel: W2f -> bf16 ----------------
__global__ void k_conv(const float* __restrict__ w2f, __hip_bfloat16* __restrict__ w2b) {
  int i = blockIdx.x * 256 + threadIdx.x;
  if (i < D_ * P_) w2b[i] = __float2bfloat16(w2f[i]);
}

// ---------------- kernel: LayerNorm + gather -> g (bf16 [N_,P_]) ----------------
__global__ __launch_bounds__(256) void k_ln_gather(
    const float* __restrict__ x, const float* __restrict__ lnw,
    const float* __restrict__ lnb, const int* __restrict__ s3,
    __hip_bfloat16* __restrict__ g) {
  __shared__ float row[D_];
  __shared__ float psum[4], psum2[4];
  const int n = blockIdx.x;
  const int t = threadIdx.x;
  const float* xr = x + (size_t)n * D_;
  float4 v = ((const float4*)xr)[t];       // 256 threads * 4 floats = 1024
  ((float4*)row)[t] = v;
  float s  = v.x + v.y + v.z + v.w;
  float s2 = v.x*v.x + v.y*v.y + v.z*v.z + v.w*v.w;
  #pragma unroll
  for (int off = 32; off > 0; off >>= 1) {
    s  += __shfl_down(s, off);
    s2 += __shfl_down(s2, off);
  }
  const int lane = t & 63, wid = t >> 6;
  if (lane == 0) { psum[wid] = s; psum2[wid] = s2; }
  __syncthreads();
  const float tot  = psum[0] + psum[1] + psum[2] + psum[3];
  const float tot2 = psum2[0] + psum2[1] + psum2[2] + psum2[3];
  const float mu  = tot * (1.f / D_);
  const float var = tot2 * (1.f / D_) - mu * mu;
  const float inv = rsqrtf(var + LN_EPS);
  __hip_bfloat16* gr = g + (size_t)n * P_;
  // two gathered outputs per thread, one 4B store
  const int i0 = s3[2*t], i1 = s3[2*t+1];
  const float v0 = (row[i0] - mu) * inv * lnw[i0] + lnb[i0];
  const float v1 = (row[i1] - mu) * inv * lnw[i1] + lnb[i1];
  union { __hip_bfloat16 h; unsigned short u; } c0, c1;
  c0.h = __float2bfloat16(v0);
  c1.h = __float2bfloat16(v1);
  unsigned int packed = (unsigned int)c0.u | ((unsigned int)c1.u << 16);
  ((unsigned int*)gr)[t] = packed;
}

// ---------------- kernel: bf16 MFMA GEMM + residual + bias ----------------
// out[n,c] = hid[n,c] + sum_p g[n,p]*W2[c,p] + b2[c]
// 128x128 tile, BK=64, DOUBLE-buffered LDS (64KB -> 2 blocks/CU), 8 waves
// (2x4 grid, 64x32 wave tile), 16x16x32 bf16 MFMA, acc 4x2.
// 2-phase schedule (T3 minimum): one barrier per K-step; STAGE(ks+1) issued
// right after the barrier so its vmcnt drain (at the NEXT barrier) hides
// under this step's ds_read + 32 MFMA.
// LDS rows 128B, XOR swizzle byte^=((row&7)<<4) applied on the pre-swizzled
// global source chunk AND the ds_read address (both-sides rule; 0 conflicts
// measured in round 1).
#define BM 128
#define BN 128
#define BK 64

__global__ __launch_bounds__(512, 4) void k_gemm(
    const __hip_bfloat16* __restrict__ g,    // [N_,P_]
    const __hip_bfloat16* __restrict__ w2b,  // [D_,P_]
    const float* __restrict__ b2,            // [D_]
    const float* __restrict__ hid,           // [N_,D_]
    float* __restrict__ out) {               // [N_,D_]
  __shared__ char At[2][BM * BK * 2];        // 2 x 16KB
  __shared__ char Bt[2][BN * BK * 2];        // 2 x 16KB

  // XCD-aware swizzle (proven round 2: FETCH 202->148 MB): XCD x gets 32
  // contiguous bm strips; the 8 bn-siblings of each strip stay on one XCD.
  const int bid = blockIdx.x;                // 0..2047
  const int x = bid & 7;
  const int kq = bid >> 3;                   // 0..255
  const int bm = (x * 32 + (kq >> 3)) * BM;
  const int bn = (kq & 7) * BN;

  const int t = threadIdx.x;
  const int lane = t & 63;
  const int wid = t >> 6;                    // 8 waves
  const int wr = wid >> 2, wc = wid & 3;     // 2x4 waves, 64x32 subtile each

  f32x4 acc[4][2] = {};

  // stage tile ks into buf: 1024 chunks of 16B per operand, 2 per thread each
  #define STAGE(ks, buf)                                                      \
    {                                                                         \
      const int k0 = (ks) * BK;                                               \
      _Pragma("unroll")                                                       \
      for (int i = 0; i < 2; ++i) {                                           \
        int ch = t + i * 512;                 /* 0..1023 */                    \
        int r  = ch >> 3;                     /* tile row, 8 x 16B per 128B row */ \
        int cc = ch & 7;                                                      \
        int col = ((cc ^ (r & 7)) << 3);      /* pre-swizzled src col (bf16) */ \
        gload_lds16(g   + (size_t)(bm + r) * P_ + k0 + col, At[buf] + ch * 16); \
        gload_lds16(w2b + (size_t)(bn + r) * P_ + k0 + col, Bt[buf] + ch * 16); \
      }                                                                       \
    }

  STAGE(0, 0);
  for (int ks = 0; ks < 8; ++ks) {
    const int buf = ks & 1;
    __syncthreads();                   // drains the stage issued last iter
    if (ks < 7) STAGE(ks + 1, buf ^ 1);  // latency hides under this compute

    bf16x8 af[2][4], bfr[2][2];
    #pragma unroll
    for (int kk = 0; kk < 2; ++kk) {
      const int colb = kk * 64 + ((lane >> 4) << 4);   // byte offset in row
      #pragma unroll
      for (int mi = 0; mi < 4; ++mi) {
        const int r = wr * 64 + mi * 16 + (lane & 15);
        af[kk][mi] = *(const bf16x8*)(At[buf] + ((r * 128 + colb) ^ ((r & 7) << 4)));
      }
      #pragma unroll
      for (int ni = 0; ni < 2; ++ni) {
        const int r = wc * 32 + ni * 16 + (lane & 15);
        bfr[kk][ni] = *(const bf16x8*)(Bt[buf] + ((r * 128 + colb) ^ ((r & 7) << 4)));
      }
    }
    #pragma unroll
    for (int kk = 0; kk < 2; ++kk)
      #pragma unroll
      for (int mi = 0; mi < 4; ++mi)
        #pragma unroll
        for (int ni = 0; ni < 2; ++ni)
          acc[mi][ni] = __builtin_amdgcn_mfma_f32_16x16x32_bf16(
              af[kk][mi], bfr[kk][ni], acc[mi][ni], 0, 0, 0);
  }

  // epilogue: C/D layout col=lane&15 (N), row=(lane>>4)*4+reg (M).
  // nontemporal: don't evict g/w2b from the XCD L2.
  const int row0 = bm + wr * 64 + ((lane >> 4) << 2);
  const int col0 = bn + wc * 32 + (lane & 15);
  #pragma unroll
  for (int ni = 0; ni < 2; ++ni) {
    const int col = col0 + ni * 16;
    const float bias = b2[col];
    #pragma unroll
    for (int mi = 0; mi < 4; ++mi) {
      const int rw = row0 + mi * 16;
      #pragma unroll
      for (int r4 = 0; r4 < 4; ++r4) {
        const size_t idx = (size_t)(rw + r4) * D_ + col;
        const float h = __builtin_nontemporal_load(hid + idx);
        __builtin_nontemporal_store(h + acc[mi][ni][r4] + bias, out + idx);
      }
    }
  }
}

extern "C" void kernel_launch(void* const* d_in, const int* in_sizes, int n_in,
                              void* d_out, int out_size, void* d_ws, size_t ws_size,
                              hipStream_t stream) {
  const float* hid  = (const float*)d_in[0];
  const float* lnw  = (const float*)d_in[1];
  const float* lnb  = (const float*)d_in[2];
  const float* W    = (const float*)d_in[3];
  const float* bias = (const float*)d_in[4];
  const int*   s3   = (const int*)d_in[5];
  const int*   s5   = (const int*)d_in[6];
  float* out = (float*)d_out;

  // workspace layout:
  //   [0, 2MB)            W2f  fp32 [1024][512]
  //   [2MB, +4KB)         b2   fp32 [1024]
  //   [2MB+4KB, +1MB)     W2b  bf16 [1024][512]
  //   [3MB+4KB, +32MB)    g    bf16 [32768][512]
  char* ws = (char*)d_ws;
  float*          w2f = (float*)ws;
  float*          b2  = (float*)(ws + 2097152);
  __hip_bfloat16* w2b = (__hip_bfloat16*)(ws + 2101248);
  __hip_bfloat16* g   = (__hip_bfloat16*)(ws + 3149824);

  hipMemsetAsync(ws, 0, 2101248, stream);   // zero W2f + b2
  k_scatter<<<dim3(1024), dim3(256), 0, stream>>>(W, bias, s5, w2f, b2);
  k_conv   <<<dim3(2048), dim3(256), 0, stream>>>(w2f, w2b);
  k_ln_gather<<<dim3(N_), dim3(256), 0, stream>>>(hid, lnw, lnb, s3, g);
  k_gemm   <<<dim3(2048), dim3(512), 0, stream>>>(g, w2b, b2, hid, out);
}

// Round 6
// 122.018 us; speedup vs baseline: 2.4444x; 1.2357x over previous
//
#include <hip/hip_runtime.h>
#include <hip/hip_bf16.h>
#include <stdint.h>

#define LN_EPS 1e-5f

typedef __attribute__((ext_vector_type(4))) float f32x4;
typedef __attribute__((ext_vector_type(8))) short bf16x8;

#define D_ 1024
#define P_ 512
#define N_ 32768   // B*S rows

// async global->LDS, 16B per lane
__device__ __forceinline__ void gload_lds16(const void* gsrc, void* ldst) {
  __builtin_amdgcn_global_load_lds(
      (const __attribute__((address_space(1))) void*)gsrc,
      (__attribute__((address_space(3))) void*)ldst,
      16, 0, 0);
}

// ---------------- kernel: scatter W rows into W2f ----------------
// W2f[c,p] = sum_{d: s5[d]==c} W[d,p];  b2[c] = sum_{d: s5[d]==c} b[d]
__global__ void k_scatter(const float* __restrict__ W, const float* __restrict__ bias,
                          const int* __restrict__ s5,
                          float* __restrict__ w2f, float* __restrict__ b2) {
  int d = blockIdx.x;                  // 0..1023
  int c = s5[d];
  const float* wrow = W + (size_t)d * P_;
  float* dst = w2f + (size_t)c * P_;
  for (int p = threadIdx.x; p < P_; p += 256)
    atomicAdd(&dst[p], wrow[p]);
  if (threadIdx.x == 0) atomicAdd(&b2[c], bias[d]);
}

// ---------------- kernel: W2f -> bf16 ----------------
__global__ void k_conv(const float* __restrict__ w2f, __hip_bfloat16* __restrict__ w2b) {
  int i = blockIdx.x * 256 + threadIdx.x;
  if (i < D_ * P_) w2b[i] = __float2bfloat16(w2f[i]);
}

// ---------------- kernel: LayerNorm + gather -> g (bf16 [N_,P_]) ----------------
__global__ __launch_bounds__(256) void k_ln_gather(
    const float* __restrict__ x, const float* __restrict__ lnw,
    const float* __restrict__ lnb, const int* __restrict__ s3,
    __hip_bfloat16* __restrict__ g) {
  __shared__ float row[D_];
  __shared__ float psum[4], psum2[4];
  const int n = blockIdx.x;
  const int t = threadIdx.x;
  const float* xr = x + (size_t)n * D_;
  float4 v = ((const float4*)xr)[t];       // 256 threads * 4 floats = 1024
  ((float4*)row)[t] = v;
  float s  = v.x + v.y + v.z + v.w;
  float s2 = v.x*v.x + v.y*v.y + v.z*v.z + v.w*v.w;
  #pragma unroll
  for (int off = 32; off > 0; off >>= 1) {
    s  += __shfl_down(s, off);
    s2 += __shfl_down(s2, off);
  }
  const int lane = t & 63, wid = t >> 6;
  if (lane == 0) { psum[wid] = s; psum2[wid] = s2; }
  __syncthreads();
  const float tot  = psum[0] + psum[1] + psum[2] + psum[3];
  const float tot2 = psum2[0] + psum2[1] + psum2[2] + psum2[3];
  const float mu  = tot * (1.f / D_);
  const float var = tot2 * (1.f / D_) - mu * mu;
  const float inv = rsqrtf(var + LN_EPS);
  __hip_bfloat16* gr = g + (size_t)n * P_;
  // two gathered outputs per thread, one 4B store
  const int i0 = s3[2*t], i1 = s3[2*t+1];
  const float v0 = (row[i0] - mu) * inv * lnw[i0] + lnb[i0];
  const float v1 = (row[i1] - mu) * inv * lnw[i1] + lnb[i1];
  union { __hip_bfloat16 h; unsigned short u; } c0, c1;
  c0.h = __float2bfloat16(v0);
  c1.h = __float2bfloat16(v1);
  unsigned int packed = (unsigned int)c0.u | ((unsigned int)c1.u << 16);
  ((unsigned int*)gr)[t] = packed;
}

// ---------------- kernel: bf16 MFMA GEMM + residual + bias ----------------
// out[n,c] = hid[n,c] + sum_p g[n,p]*W2[c,p] + b2[c]
// 128x128 tile, BK=64, double-buffered LDS (64KB), 8 waves (2x4, 64x32 wave
// tile), 16x16x32 bf16 MFMA, acc 4x2. 2-phase schedule: one barrier per
// K-step; STAGE(ks+1) issued right after the barrier so its vmcnt drain (at
// the NEXT barrier) hides under this step's ds_read + 32 MFMA.
// EPILOGUE (new): acc tile bounced through the dead 64KB LDS (exactly
// 128x128 f32), read back as float4/lane -> hid-load / out-store become two
// contiguous 512B segments per wave instruction instead of 16x64B fragments.
#define BM 128
#define BN 128
#define BK 64

__global__ __launch_bounds__(512, 4) void k_gemm(
    const __hip_bfloat16* __restrict__ g,    // [N_,P_]
    const __hip_bfloat16* __restrict__ w2b,  // [D_,P_]
    const float* __restrict__ b2,            // [D_]
    const float* __restrict__ hid,           // [N_,D_]
    float* __restrict__ out) {               // [N_,D_]
  __shared__ __align__(16) char smem[65536]; // At[2][16K] | Bt[2][16K] == ctile f32[128][128]
  char* At[2] = { smem,         smem + 16384 };
  char* Bt[2] = { smem + 32768, smem + 49152 };
  float* ctile = (float*)smem;

  // XCD-aware swizzle (proven: FETCH 202->132 MB): XCD x gets 32 contiguous
  // bm strips; the 8 bn-siblings of each strip stay on one XCD.
  const int bid = blockIdx.x;                // 0..2047
  const int x = bid & 7;
  const int kq = bid >> 3;                   // 0..255
  const int bm = (x * 32 + (kq >> 3)) * BM;
  const int bn = (kq & 7) * BN;

  const int t = threadIdx.x;
  const int lane = t & 63;
  const int wid = t >> 6;                    // 8 waves
  const int wr = wid >> 2, wc = wid & 3;     // 2x4 waves, 64x32 subtile each

  f32x4 acc[4][2] = {};

  // stage tile ks into buf: 1024 chunks of 16B per operand, 2 per thread each
  #define STAGE(ks, buf)                                                      \
    {                                                                         \
      const int k0 = (ks) * BK;                                               \
      _Pragma("unroll")                                                       \
      for (int i = 0; i < 2; ++i) {                                           \
        int ch = t + i * 512;                 /* 0..1023 */                    \
        int r  = ch >> 3;                     /* tile row, 8 x 16B per 128B row */ \
        int cc = ch & 7;                                                      \
        int col = ((cc ^ (r & 7)) << 3);      /* pre-swizzled src col (bf16) */ \
        gload_lds16(g   + (size_t)(bm + r) * P_ + k0 + col, At[buf] + ch * 16); \
        gload_lds16(w2b + (size_t)(bn + r) * P_ + k0 + col, Bt[buf] + ch * 16); \
      }                                                                       \
    }

  STAGE(0, 0);
  for (int ks = 0; ks < 8; ++ks) {
    const int buf = ks & 1;
    __syncthreads();                   // drains the stage issued last iter
    if (ks < 7) STAGE(ks + 1, buf ^ 1);  // latency hides under this compute

    bf16x8 af[2][4], bfr[2][2];
    #pragma unroll
    for (int kk = 0; kk < 2; ++kk) {
      const int colb = kk * 64 + ((lane >> 4) << 4);   // byte offset in row
      #pragma unroll
      for (int mi = 0; mi < 4; ++mi) {
        const int r = wr * 64 + mi * 16 + (lane & 15);
        af[kk][mi] = *(const bf16x8*)(At[buf] + ((r * 128 + colb) ^ ((r & 7) << 4)));
      }
      #pragma unroll
      for (int ni = 0; ni < 2; ++ni) {
        const int r = wc * 32 + ni * 16 + (lane & 15);
        bfr[kk][ni] = *(const bf16x8*)(Bt[buf] + ((r * 128 + colb) ^ ((r & 7) << 4)));
      }
    }
    #pragma unroll
    for (int kk = 0; kk < 2; ++kk)
      #pragma unroll
      for (int mi = 0; mi < 4; ++mi)
        #pragma unroll
        for (int ni = 0; ni < 2; ++ni)
          acc[mi][ni] = __builtin_amdgcn_mfma_f32_16x16x32_bf16(
              af[kk][mi], bfr[kk][ni], acc[kk ? mi : mi][ni], 0, 0, 0);
  }

  // ===== epilogue =====
  __syncthreads();   // all LDS reads of At/Bt done; smem becomes ctile
  // write acc fragments to ctile. C/D layout: col=lane&15, row=(lane>>4)*4+r4.
  // col-XOR ((row>>2)&1)<<4 splits the 4 lane-groups across banks 0-15/16-31
  // (2-way = free) and preserves float4 contiguity on readback.
  #pragma unroll
  for (int ni = 0; ni < 2; ++ni) {
    #pragma unroll
    for (int mi = 0; mi < 4; ++mi) {
      #pragma unroll
      for (int r4 = 0; r4 < 4; ++r4) {
        const int row = wr * 64 + mi * 16 + ((lane >> 4) << 2) + r4;
        const int col = wc * 32 + ni * 16 + (lane & 15);
        ctile[row * 128 + (col ^ (((row >> 2) & 1) << 4))] = acc[mi][ni][r4];
      }
    }
  }
  __syncthreads();
  // read back float4/lane; fully-coalesced streaming add of hid + b2 -> out
  #pragma unroll
  for (int i = 0; i < 8; ++i) {
    const int idx = i * 512 + t;           // 0..4095 float4 slots
    const int row = idx >> 5;              // 0..127
    const int j0  = (idx & 31) << 2;       // col start (multiple of 4)
    const int swz = ((row >> 2) & 1) << 4;
    const f32x4 a = *(const f32x4*)&ctile[row * 128 + (j0 ^ swz)];
    const f32x4 bias = *(const f32x4*)(b2 + bn + j0);
    const size_t gidx = (size_t)(bm + row) * D_ + bn + j0;
    const f32x4 h = __builtin_nontemporal_load((const f32x4*)(hid + gidx));
    f32x4 o;
    o.x = h.x + a.x + bias.x;
    o.y = h.y + a.y + bias.y;
    o.z = h.z + a.z + bias.z;
    o.w = h.w + a.w + bias.w;
    __builtin_nontemporal_store(o, (f32x4*)(out + gidx));
  }
}

extern "C" void kernel_launch(void* const* d_in, const int* in_sizes, int n_in,
                              void* d_out, int out_size, void* d_ws, size_t ws_size,
                              hipStream_t stream) {
  const float* hid  = (const float*)d_in[0];
  const float* lnw  = (const float*)d_in[1];
  const float* lnb  = (const float*)d_in[2];
  const float* W    = (const float*)d_in[3];
  const float* bias = (const float*)d_in[4];
  const int*   s3   = (const int*)d_in[5];
  const int*   s5   = (const int*)d_in[6];
  float* out = (float*)d_out;

  // workspace layout:
  //   [0, 2MB)            W2f  fp32 [1024][512]
  //   [2MB, +4KB)         b2   fp32 [1024]
  //   [2MB+4KB, +1MB)     W2b  bf16 [1024][512]
  //   [3MB+4KB, +32MB)    g    bf16 [32768][512]
  char* ws = (char*)d_ws;
  float*          w2f = (float*)ws;
  float*          b2  = (float*)(ws + 2097152);
  __hip_bfloat16* w2b = (__hip_bfloat16*)(ws + 2101248);
  __hip_bfloat16* g   = (__hip_bfloat16*)(ws + 3149824);

  hipMemsetAsync(ws, 0, 2101248, stream);   // zero W2f + b2
  k_scatter<<<dim3(1024), dim3(256), 0, stream>>>(W, bias, s5, w2f, b2);
  k_conv   <<<dim3(2048), dim3(256), 0, stream>>>(w2f, w2b);
  k_ln_gather<<<dim3(N_), dim3(256), 0, stream>>>(hid, lnw, lnb, s3, g);
  k_gemm   <<<dim3(2048), dim3(512), 0, stream>>>(g, w2b, b2, hid, out);
}